// Round 1
// 412.058 us; speedup vs baseline: 1.0536x; 1.0536x over previous
//
#include <hip/hip_runtime.h>
#include <math.h>

#define NPTS 262144
#define MT 64          // points per block

typedef __attribute__((ext_vector_type(8))) short bf16x8;
typedef __attribute__((ext_vector_type(4))) float f32x4;
typedef __attribute__((ext_vector_type(2))) unsigned int u32x2;

#if defined(__has_builtin)
#if __has_builtin(__builtin_amdgcn_cvt_pk_bf16_f32)
#define HAVE_CVT_PK_BF16 1
#endif
#endif

__device__ __forceinline__ short f2bf(float f) {
    union { float f; unsigned u; } v; v.f = f;
    unsigned r = v.u + 0x7fffu + ((v.u >> 16) & 1u);   // RNE
    return (short)(r >> 16);
}
__device__ __forceinline__ unsigned pk2(float a, float b) {
#ifdef HAVE_CVT_PK_BF16
    auto r = __builtin_amdgcn_cvt_pk_bf16_f32(a, b);   // 1 instr, RNE
    unsigned u; __builtin_memcpy(&u, &r, 4);
    return u;
#else
    return ((unsigned)(unsigned short)f2bf(a)) |
           ((unsigned)(unsigned short)f2bf(b) << 16);
#endif
}

// ---- swizzled-weight workspace layout (offsets in bf16 elements) ----
#define OFF_IN   0
#define SZ_IN    (64*256)
#define OFF_H0   (OFF_IN + SZ_IN)
#define SZ_H     (256*256)
#define OFF_H1   (OFF_H0 + SZ_H)
#define OFF_H2   (OFF_H1 + SZ_H)
#define OFF_H3   (OFF_H2 + SZ_H)
#define OFF_H4   (OFF_H3 + SZ_H)
#define SZ_H4    (320*256)
#define OFF_H5   (OFF_H4 + SZ_H4)
#define OFF_H6   (OFF_H5 + SZ_H)
#define OFF_OUT  (OFF_H6 + SZ_H)
#define SZ_OUT   (256*272)          // N padded to 272 = 17 tiles (density tile = 16)
#define OFF_R1   (OFF_OUT + SZ_OUT)
#define SZ_R1    (288*128)
#define OFF_R2   (OFF_R1 + SZ_R1)
#define SZ_R2    (128*16)
#define WS_TOTAL (OFF_R2 + SZ_R2)

// ---------------- weight prep: f32 -> bf16, 16x16x32 fragment swizzle -------
// frag tile (kt,nt): elem ((kt*nNt + nt)*64 + lane)*8 + j
//   holds W[kt*32 + (lane>>4)*8 + j][nt*16 + (lane&15)]  (0-padded)
// Used as A operand of A=W^T (rows = output feature n): A[m=lane&15][k=quad*8+j].
struct PrepP { const float* W[11]; short* ws; };

__global__ __launch_bounds__(256) void prep_all(PrepP pp) {
    int i = blockIdx.x * 256 + threadIdx.x;
    if (i >= WS_TOTAL) return;
    const int offs[12] = {OFF_IN, OFF_H0, OFF_H1, OFF_H2, OFF_H3, OFF_H4,
                          OFF_H5, OFF_H6, OFF_OUT, OFF_R1, OFF_R2, WS_TOTAL};
    const int Ks[11]  = {63,256,256,256,256,319,256,256,256,283,128};
    const int Ns[11]  = {256,256,256,256,256,256,256,256,257,128,3};
    const int Nps[11] = {256,256,256,256,256,256,256,256,272,128,16};
    int seg = 0;
    while (i >= offs[seg + 1]) seg++;
    int li = i - offs[seg];
    int j = li & 7, L = (li >> 3) & 63, tile = li >> 9;
    int nNt = Nps[seg] >> 4;
    int nt = tile % nNt, kt = tile / nNt;
    int k = kt * 32 + ((L >> 4) << 3) + j;
    int n = nt * 16 + (L & 15);
    float v = (k < Ks[seg] && n < Ns[seg]) ? pp.W[seg][k * Ns[seg] + n] : 0.f;
    pp.ws[i] = f2bf(v);
}

// ---------------- fused MLP ----------------
struct Params {
    const float *pos, *dir;
    const float *b_in, *b_h0, *b_h1, *b_h2, *b_h3, *b_h4, *b_h5, *b_h6;
    const float *b_out, *b_r1, *b_r2;
    const short *w;
    float *out;
};

// X LDS layout: k-grouped B-fragment layout (element (k,m) of the activation
// matrix X[m][k] stored at short index ((k>>3)*64 + m)*8 + (k&7)).
//  - b128 reads for the MFMA B operand: 16B slot = l15&7 -> conflict-free by
//    construction, and every read is base-VGPR + 16-bit immediate (0 addr VALU).
//  - 40 k-groups (320 cols incl. pe-skip copy) x 64 pts x 16B = 40960 B exact,
//    no pad needed -> 2 blocks/CU at 512 threads with <=128 VGPRs.
//
// Transposed MFMA: A = W^T (rows = feature n), B = X^T (cols = point m).
// C layout: row(quad*4+r) = n-in-tile, col(l15) = m-in-tile.
// 8 waves/block; wave covers NS n-tiles x all 4 m-tiles.
// K-loop software-pipelined (dist-1 double buffers for a [L2] and b [LDS]);
// regs: acc 16*NS + 8*(NS+4)*2 approx 95 < 128 cap at (512,4).
// MODE 0: relu -> X.  MODE 1: out layer: features (no relu) -> X; density row
// (tile 16, n==256) via transient pre-pass on waves 0..3 straight to gmem.
template<int NKT, int NT, int NS, int MODE>
__device__ __forceinline__ void layerT(const short* __restrict__ Wsw,
                                       const float* __restrict__ bias,
                                       short* X, float* dout, int p0,
                                       int ntB, int wave, int lane) {
    const int l15 = lane & 15, quad = lane >> 4;
    __syncthreads();                      // X (this layer's input) is ready
    const short* xb = X + quad * 512 + l15 * 8;   // + t*128 + kt*2048

    if (MODE == 1 && wave < 4) {          // density pre-pass: m-tile = wave
        f32x4 ad = (f32x4){0.f, 0.f, 0.f, 0.f};
#pragma unroll
        for (int kt = 0; kt < NKT; ++kt) {
            bf16x8 b = *(const bf16x8*)(xb + wave * 128 + kt * 2048);
            bf16x8 a = *(const bf16x8*)(Wsw + (size_t)((kt * NT + 16) * 64 + lane) * 8);
            ad = __builtin_amdgcn_mfma_f32_16x16x32_bf16(a, b, ad, 0, 0, 0);
        }
        if (quad == 0)                    // C row 0 = n 256 (density)
            dout[3 * NPTS + p0 + wave * 16 + l15] = fmaxf(ad[0] + bias[256], 0.f);
    }

    f32x4 acc[NS][4];
#pragma unroll
    for (int s = 0; s < NS; s++)
#pragma unroll
        for (int t = 0; t < 4; t++) acc[s][t] = (f32x4){0.f, 0.f, 0.f, 0.f};

    const short* wp = Wsw + (size_t)(ntB * 64 + lane) * 8;   // advances by NT*512/kt

    bf16x8 a_c[NS], b_c[4];
#pragma unroll
    for (int s = 0; s < NS; s++)
        a_c[s] = *(const bf16x8*)(wp + (size_t)s * 512);
#pragma unroll
    for (int t = 0; t < 4; t++)
        b_c[t] = *(const bf16x8*)(xb + t * 128);

#pragma unroll
    for (int kt = 0; kt < NKT; ++kt) {
        bf16x8 a_n[NS], b_n[4];
        if (kt + 1 < NKT) {               // prefetch kt+1 before consuming kt
            const short* wp1 = wp + (size_t)(kt + 1) * NT * 512;
#pragma unroll
            for (int s = 0; s < NS; s++)
                a_n[s] = *(const bf16x8*)(wp1 + (size_t)s * 512);
#pragma unroll
            for (int t = 0; t < 4; t++)
                b_n[t] = *(const bf16x8*)(xb + (kt + 1) * 2048 + t * 128);
        }
#pragma unroll
        for (int s = 0; s < NS; s++)
#pragma unroll
            for (int t = 0; t < 4; t++)
                acc[s][t] = __builtin_amdgcn_mfma_f32_16x16x32_bf16(a_c[s], b_c[t], acc[s][t], 0, 0, 0);
        if (kt + 1 < NKT) {
#pragma unroll
            for (int s = 0; s < NS; s++) a_c[s] = a_n[s];
#pragma unroll
            for (int t = 0; t < 4; t++) b_c[t] = b_n[t];
        }
    }
    __syncthreads();                      // all reads of X done; safe to overwrite
#pragma unroll
    for (int s = 0; s < NS; s++) {
        const int n0 = (ntB + s) * 16 + quad * 4;
        const f32x4 bv = *(const f32x4*)(bias + n0);
        // value (n, m) -> short idx ((n>>3)*64 + m)*8 + (n&7);
        // 4 accs (r=0..3) are contiguous shorts -> one u32x2 per tile
        short* xo = X + (2 * (ntB + s) + (quad >> 1)) * 512 + (quad & 1) * 4;
#pragma unroll
        for (int t = 0; t < 4; t++) {
            const int m = t * 16 + l15;
            float v0 = acc[s][t][0] + bv[0];
            float v1 = acc[s][t][1] + bv[1];
            float v2 = acc[s][t][2] + bv[2];
            float v3 = acc[s][t][3] + bv[3];
            if (MODE == 0) {
                v0 = fmaxf(v0, 0.f); v1 = fmaxf(v1, 0.f);
                v2 = fmaxf(v2, 0.f); v3 = fmaxf(v3, 0.f);
            }
            u32x2 w; w[0] = pk2(v0, v1); w[1] = pk2(v2, v3);
            *(u32x2*)(xo + m * 8) = w;
        }
    }
}

__global__ __launch_bounds__(512, 4) void nerf_fused(Params P) {
    __shared__ __align__(16) short X[40 * 512];   // 20480 shorts = 40960 B exact
    const int tid = threadIdx.x;
    const int wave = tid >> 6, lane = tid & 63;
    const int p0 = blockIdx.x * MT;

    // hidden/out layers: 8 waves x NS=2 n-tiles (x all 4 m-tiles)
    const int ntB_h = wave * 2;

    // ---- positional encoding (d is wave-uniform: uniform branches, and
    //      stores stride 16B -> conflict-free) ----
    for (int i = tid; i < MT * 64; i += 512) {
        const int pt = i & 63, d = i >> 6;
        float v = 0.f;
        if (d < 3) v = P.pos[(p0 + pt) * 3 + d];
        else if (d < 63) {
            const int e = d - 3, f = e / 6, r = e % 6;
            const float x = P.pos[(p0 + pt) * 3 + (r % 3)];
            const float xf = x * (float)(1 << f);
            v = (r < 3) ? sinf(xf) : cosf(xf);
        }
        const short bv = f2bf(v);
        X[((d >> 3) * 64 + pt) * 8 + (d & 7)] = bv;          // input-layer cols
        X[((32 + (d >> 3)) * 64 + pt) * 8 + (d & 7)] = bv;   // h4 skip copy (cols 256+)
    }

    layerT<2, 16, 2, 0>(P.w + OFF_IN, P.b_in, X, P.out, p0, ntB_h, wave, lane);
    layerT<8, 16, 2, 0>(P.w + OFF_H0, P.b_h0, X, P.out, p0, ntB_h, wave, lane);
    layerT<8, 16, 2, 0>(P.w + OFF_H1, P.b_h1, X, P.out, p0, ntB_h, wave, lane);
    layerT<8, 16, 2, 0>(P.w + OFF_H2, P.b_h2, X, P.out, p0, ntB_h, wave, lane);
    layerT<8, 16, 2, 0>(P.w + OFF_H3, P.b_h3, X, P.out, p0, ntB_h, wave, lane);
    layerT<10, 16, 2, 0>(P.w + OFF_H4, P.b_h4, X, P.out, p0, ntB_h, wave, lane); // concat
    layerT<8, 16, 2, 0>(P.w + OFF_H5, P.b_h5, X, P.out, p0, ntB_h, wave, lane);
    layerT<8, 16, 2, 0>(P.w + OFF_H6, P.b_h6, X, P.out, p0, ntB_h, wave, lane);
    layerT<8, 17, 2, 1>(P.w + OFF_OUT, P.b_out, X, P.out, p0, ntB_h, wave, lane);

    // dir-enc computed in place into cols 256..287 (k-groups 32..35; disjoint
    // from out-layer feature writes (groups 0..31); ordered before r1's K-loop
    // by r1's entry barrier; cols 283..287 are real zeros)
    for (int i = tid; i < MT * 32; i += 512) {
        const int pt = i & 63, d = i >> 6;
        float v = 0.f;
        if (d < 3) v = P.dir[(p0 + pt) * 3 + d];
        else if (d < 27) {
            const int e = d - 3, f = e / 6, r = e % 6;
            const float x = P.dir[(p0 + pt) * 3 + (r % 3)];
            const float xf = x * (float)(1 << f);
            v = (r < 3) ? sinf(xf) : cosf(xf);
        }
        X[((32 + (d >> 3)) * 64 + pt) * 8 + (d & 7)] = f2bf(v);
    }

    // r1: 8 n-tiles / 8 waves -> NS=1
    layerT<9, 8, 1, 0>(P.w + OFF_R1, P.b_r1, X, P.out, p0, wave, wave, lane);

    // ---- r2 (128 -> 3) + sigmoid; waves 0..3 each take one 16-point tile ----
    __syncthreads();
    if (wave < 4) {
        const int l15 = lane & 15, quad = lane >> 4;
        f32x4 acc = (f32x4){0.f, 0.f, 0.f, 0.f};
        const short* xb = X + quad * 512 + (wave * 16 + l15) * 8;
#pragma unroll
        for (int kt = 0; kt < 4; ++kt) {
            bf16x8 b = *(const bf16x8*)(xb + kt * 2048);
            bf16x8 a = *(const bf16x8*)(P.w + OFF_R2 + (size_t)(kt * 64 + lane) * 8);
            acc = __builtin_amdgcn_mfma_f32_16x16x32_bf16(a, b, acc, 0, 0, 0);
        }
        if (quad == 0) {                   // rows r = rgb channel
#pragma unroll
            for (int r = 0; r < 3; r++) {
                const float v = acc[r] + P.b_r2[r];
                P.out[(size_t)(p0 + wave * 16 + l15) * 3 + r] = 1.f / (1.f + expf(-v));
            }
        }
    }
}

extern "C" void kernel_launch(void* const* d_in, const int* in_sizes, int n_in,
                              void* d_out, int out_size, void* d_ws, size_t ws_size,
                              hipStream_t stream) {
    short* ws = (short*)d_ws;

    PrepP pp;
    pp.W[0]  = (const float*)d_in[2];   // W_in
    pp.W[1]  = (const float*)d_in[4];   // W_h0
    pp.W[2]  = (const float*)d_in[6];   // W_h1
    pp.W[3]  = (const float*)d_in[8];   // W_h2
    pp.W[4]  = (const float*)d_in[10];  // W_h3
    pp.W[5]  = (const float*)d_in[12];  // W_h4
    pp.W[6]  = (const float*)d_in[14];  // W_h5
    pp.W[7]  = (const float*)d_in[16];  // W_h6
    pp.W[8]  = (const float*)d_in[18];  // W_out
    pp.W[9]  = (const float*)d_in[20];  // W_r1
    pp.W[10] = (const float*)d_in[22];  // W_r2
    pp.ws = ws;
    hipLaunchKernelGGL(prep_all, dim3((WS_TOTAL + 255) / 256), dim3(256), 0, stream, pp);

    Params P;
    P.pos  = (const float*)d_in[0];
    P.dir  = (const float*)d_in[1];
    P.b_in = (const float*)d_in[3];
    P.b_h0 = (const float*)d_in[5];
    P.b_h1 = (const float*)d_in[7];
    P.b_h2 = (const float*)d_in[9];
    P.b_h3 = (const float*)d_in[11];
    P.b_h4 = (const float*)d_in[13];
    P.b_h5 = (const float*)d_in[15];
    P.b_h6 = (const float*)d_in[17];
    P.b_out = (const float*)d_in[19];
    P.b_r1 = (const float*)d_in[21];
    P.b_r2 = (const float*)d_in[23];
    P.w = ws;
    P.out = (float*)d_out;
    hipLaunchKernelGGL(nerf_fused, dim3(NPTS / MT), dim3(512), 0, stream, P);
}

// Round 2
// 409.417 us; speedup vs baseline: 1.0604x; 1.0065x over previous
//
#include <hip/hip_runtime.h>
#include <math.h>

#define NPTS 262144
#define MT 64          // points per block

typedef __attribute__((ext_vector_type(8))) short bf16x8;
typedef __attribute__((ext_vector_type(4))) float f32x4;
typedef __attribute__((ext_vector_type(2))) unsigned int u32x2;

#if defined(__has_builtin)
#if __has_builtin(__builtin_amdgcn_cvt_pk_bf16_f32)
#define HAVE_CVT_PK_BF16 1
#endif
#endif

__device__ __forceinline__ short f2bf(float f) {
    union { float f; unsigned u; } v; v.f = f;
    unsigned r = v.u + 0x7fffu + ((v.u >> 16) & 1u);   // RNE
    return (short)(r >> 16);
}
__device__ __forceinline__ unsigned pk2(float a, float b) {
#ifdef HAVE_CVT_PK_BF16
    auto r = __builtin_amdgcn_cvt_pk_bf16_f32(a, b);   // 1 instr, RNE
    unsigned u; __builtin_memcpy(&u, &r, 4);
    return u;
#else
    return ((unsigned)(unsigned short)f2bf(a)) |
           ((unsigned)(unsigned short)f2bf(b) << 16);
#endif
}

// ---- swizzled-weight workspace layout (offsets in bf16 elements) ----
#define OFF_IN   0
#define SZ_IN    (64*256)
#define OFF_H0   (OFF_IN + SZ_IN)
#define SZ_H     (256*256)
#define OFF_H1   (OFF_H0 + SZ_H)
#define OFF_H2   (OFF_H1 + SZ_H)
#define OFF_H3   (OFF_H2 + SZ_H)
#define OFF_H4   (OFF_H3 + SZ_H)
#define SZ_H4    (320*256)
#define OFF_H5   (OFF_H4 + SZ_H4)
#define OFF_H6   (OFF_H5 + SZ_H)
#define OFF_OUT  (OFF_H6 + SZ_H)
#define SZ_OUT   (256*272)          // N padded to 272 = 17 tiles (density tile = 16)
#define OFF_R1   (OFF_OUT + SZ_OUT)
#define SZ_R1    (288*128)
#define OFF_R2   (OFF_R1 + SZ_R1)
#define SZ_R2    (128*16)
#define WS_TOTAL (OFF_R2 + SZ_R2)

// ---------------- weight prep: f32 -> bf16, 16x16x32 fragment swizzle -------
// frag tile (kt,nt): elem ((kt*nNt + nt)*64 + lane)*8 + j
//   holds W[kt*32 + (lane>>4)*8 + j][nt*16 + (lane&15)]  (0-padded)
// Used as A operand of A=W^T (rows = output feature n): A[m=lane&15][k=quad*8+j].
struct PrepP { const float* W[11]; short* ws; };

__global__ __launch_bounds__(256) void prep_all(PrepP pp) {
    int i = blockIdx.x * 256 + threadIdx.x;
    if (i >= WS_TOTAL) return;
    const int offs[12] = {OFF_IN, OFF_H0, OFF_H1, OFF_H2, OFF_H3, OFF_H4,
                          OFF_H5, OFF_H6, OFF_OUT, OFF_R1, OFF_R2, WS_TOTAL};
    const int Ks[11]  = {63,256,256,256,256,319,256,256,256,283,128};
    const int Ns[11]  = {256,256,256,256,256,256,256,256,257,128,3};
    const int Nps[11] = {256,256,256,256,256,256,256,256,272,128,16};
    int seg = 0;
    while (i >= offs[seg + 1]) seg++;
    int li = i - offs[seg];
    int j = li & 7, L = (li >> 3) & 63, tile = li >> 9;
    int nNt = Nps[seg] >> 4;
    int nt = tile % nNt, kt = tile / nNt;
    int k = kt * 32 + ((L >> 4) << 3) + j;
    int n = nt * 16 + (L & 15);
    float v = (k < Ks[seg] && n < Ns[seg]) ? pp.W[seg][k * Ns[seg] + n] : 0.f;
    pp.ws[i] = f2bf(v);
}

// ---------------- fused MLP ----------------
struct Params {
    const float *pos, *dir;
    const float *b_in, *b_h0, *b_h1, *b_h2, *b_h3, *b_h4, *b_h5, *b_h6;
    const float *b_out, *b_r1, *b_r2;
    const short *w;
    float *out;
};

// X LDS: ping-pong pair. k-grouped B-fragment layout (element (k,m) of the
// activation matrix X[m][k] at short index ((k>>3)*64 + m)*8 + (k&7)).
//  - conflict-free b128 reads, addresses = base VGPR + 16-bit immediate.
//  - XA = 32 k-groups (256 cols), XB = 40 k-groups (320 cols: pe-skip / de
//    live in groups 32..39). 73728 B total -> 2 blocks/CU at 512 thr.
//
// Single barrier per layer: wave order is [issue a(kt=0,1) global prefetch]
// BARRIER [K-loop reads Xin] [epilogue writes Xout]. The barrier both
// publishes Xout(prev)=Xin(cur) writes and closes Xin(prev)=Xout(cur) reads.
// Weight prefetch sits in flight during barrier arrival (vmcnt drain at
// s_barrier completes it); in-loop a-prefetch is dist-2 (L2 ~200-400cy >
// one kt iter ~155cy), b-prefetch dist-1 (LDS ~120cy).
// MODE 0: relu -> Xout.  MODE 1: out layer: features (no relu) -> Xout;
// density row (tile 16, n==256) via pre-pass on waves 0..3 straight to gmem.
template<int NKT, int NT, int NS, int MODE>
__device__ __forceinline__ void layerT(const short* __restrict__ Wsw,
                                       const float* __restrict__ bias,
                                       const short* Xin, short* Xout,
                                       float* dout, int p0,
                                       int ntB, int wave, int lane) {
    const int l15 = lane & 15, quad = lane >> 4;
    const short* xb = Xin + quad * 512 + l15 * 8;   // + t*128 + kt*2048
    const short* wp = Wsw + (size_t)(ntB * 64 + lane) * 8;

    // pre-barrier: issue first two k-tiles of weight fragments (global; no
    // LDS dependency -> latency overlaps barrier arrival)
    bf16x8 a0[NS], a1[NS];
#pragma unroll
    for (int s = 0; s < NS; s++)
        a0[s] = *(const bf16x8*)(wp + (size_t)s * 512);
    if (NKT > 1)
#pragma unroll
        for (int s = 0; s < NS; s++)
            a1[s] = *(const bf16x8*)(wp + (size_t)NT * 512 + s * 512);

    __syncthreads();                      // Xin ready; Xout free to overwrite

    if (MODE == 1 && wave < 4) {          // density pre-pass: m-tile = wave
        f32x4 ad = (f32x4){0.f, 0.f, 0.f, 0.f};
#pragma unroll
        for (int kt = 0; kt < NKT; ++kt) {
            bf16x8 b = *(const bf16x8*)(xb + wave * 128 + kt * 2048);
            bf16x8 a = *(const bf16x8*)(Wsw + (size_t)((kt * NT + 16) * 64 + lane) * 8);
            ad = __builtin_amdgcn_mfma_f32_16x16x32_bf16(a, b, ad, 0, 0, 0);
        }
        if (quad == 0)                    // C row 0 = n 256 (density)
            dout[3 * NPTS + p0 + wave * 16 + l15] = fmaxf(ad[0] + bias[256], 0.f);
    }

    f32x4 acc[NS][4];
#pragma unroll
    for (int s = 0; s < NS; s++)
#pragma unroll
        for (int t = 0; t < 4; t++) acc[s][t] = (f32x4){0.f, 0.f, 0.f, 0.f};

    bf16x8 b_c[4];
#pragma unroll
    for (int t = 0; t < 4; t++)
        b_c[t] = *(const bf16x8*)(xb + t * 128);

#pragma unroll
    for (int kt = 0; kt < NKT; ++kt) {
        bf16x8 b_n[4], a_n[NS];
        if (kt + 1 < NKT) {
#pragma unroll
            for (int t = 0; t < 4; t++)
                b_n[t] = *(const bf16x8*)(xb + (kt + 1) * 2048 + t * 128);
        }
        if (kt + 2 < NKT) {
#pragma unroll
            for (int s = 0; s < NS; s++)
                a_n[s] = *(const bf16x8*)(wp + (size_t)(kt + 2) * NT * 512 + s * 512);
        }
        if ((kt & 1) == 0) {
#pragma unroll
            for (int s = 0; s < NS; s++)
#pragma unroll
                for (int t = 0; t < 4; t++)
                    acc[s][t] = __builtin_amdgcn_mfma_f32_16x16x32_bf16(a0[s], b_c[t], acc[s][t], 0, 0, 0);
        } else {
#pragma unroll
            for (int s = 0; s < NS; s++)
#pragma unroll
                for (int t = 0; t < 4; t++)
                    acc[s][t] = __builtin_amdgcn_mfma_f32_16x16x32_bf16(a1[s], b_c[t], acc[s][t], 0, 0, 0);
        }
        if (kt + 2 < NKT) {
            if ((kt & 1) == 0) {
#pragma unroll
                for (int s = 0; s < NS; s++) a0[s] = a_n[s];
            } else {
#pragma unroll
                for (int s = 0; s < NS; s++) a1[s] = a_n[s];
            }
        }
        if (kt + 1 < NKT) {
#pragma unroll
            for (int t = 0; t < 4; t++) b_c[t] = b_n[t];
        }
    }

    // epilogue -> Xout (no barrier needed: Xout reads were closed by the
    // entry barrier; next layer's entry barrier publishes these writes)
#pragma unroll
    for (int s = 0; s < NS; s++) {
        const int n0 = (ntB + s) * 16 + quad * 4;
        const f32x4 bv = *(const f32x4*)(bias + n0);
        // value (n, m) -> short idx ((n>>3)*64 + m)*8 + (n&7)
        short* xo = Xout + (2 * (ntB + s) + (quad >> 1)) * 512 + (quad & 1) * 4;
#pragma unroll
        for (int t = 0; t < 4; t++) {
            const int m = t * 16 + l15;
            float v0 = acc[s][t][0] + bv[0];
            float v1 = acc[s][t][1] + bv[1];
            float v2 = acc[s][t][2] + bv[2];
            float v3 = acc[s][t][3] + bv[3];
            if (MODE == 0) {
                v0 = fmaxf(v0, 0.f); v1 = fmaxf(v1, 0.f);
                v2 = fmaxf(v2, 0.f); v3 = fmaxf(v3, 0.f);
            }
            u32x2 w; w[0] = pk2(v0, v1); w[1] = pk2(v2, v3);
            *(u32x2*)(xo + m * 8) = w;
        }
    }
}

__global__ __launch_bounds__(512, 4) void nerf_fused(Params P) {
    __shared__ __align__(16) short XA[32 * 512];   // 32 KB (256 cols)
    __shared__ __align__(16) short XB[40 * 512];   // 40 KB (320 cols)
    const int tid = threadIdx.x;
    const int wave = tid >> 6, lane = tid & 63;
    const int p0 = blockIdx.x * MT;

    // hidden/out layers: 8 waves x NS=2 n-tiles (x all 4 m-tiles)
    const int ntB_h = wave * 2;

    // ---- positional encoding: lane owns one (pt, k-group) -> 8 cols,
    //      packed b128 stores (conflict-free; d wave-uniform branches) ----
    {
        const int pt = tid & 63, g = tid >> 6;    // g = 0..7
        const float x0 = P.pos[(p0 + pt) * 3 + 0];
        const float x1 = P.pos[(p0 + pt) * 3 + 1];
        const float x2 = P.pos[(p0 + pt) * 3 + 2];
        bf16x8 v;
#pragma unroll
        for (int j = 0; j < 8; j++) {
            const int d = g * 8 + j;
            float val = 0.f;
            if (d < 3) val = (d == 0) ? x0 : (d == 1) ? x1 : x2;
            else if (d < 63) {
                const int e = d - 3, f = e / 6, r = e % 6;
                const float x = (r % 3 == 0) ? x0 : (r % 3 == 1) ? x1 : x2;
                const float xf = x * (float)(1 << f);
                val = (r < 3) ? sinf(xf) : cosf(xf);
            }
            v[j] = f2bf(val);
        }
        *(bf16x8*)(XA + ((size_t)g * 64 + pt) * 8) = v;          // input-layer cols
        *(bf16x8*)(XB + ((size_t)(32 + g) * 64 + pt) * 8) = v;   // h4 skip (cols 256+)
    }

    // ---- dir encoding into registers (4 VGPRs, waves 0..3); spliced into
    //      XB groups 32..35 after h4's reads are closed ----
    bf16x8 de_v;
    if (wave < 4) {
        const int pt = tid & 63, g = wave;        // g = 0..3, cols 8g..8g+7
        const float x0 = P.dir[(p0 + pt) * 3 + 0];
        const float x1 = P.dir[(p0 + pt) * 3 + 1];
        const float x2 = P.dir[(p0 + pt) * 3 + 2];
#pragma unroll
        for (int j = 0; j < 8; j++) {
            const int d = g * 8 + j;
            float val = 0.f;
            if (d < 3) val = (d == 0) ? x0 : (d == 1) ? x1 : x2;
            else if (d < 27) {
                const int e = d - 3, f = e / 6, r = e % 6;
                const float x = (r % 3 == 0) ? x0 : (r % 3 == 1) ? x1 : x2;
                const float xf = x * (float)(1 << f);
                val = (r < 3) ? sinf(xf) : cosf(xf);
            }
            de_v[j] = f2bf(val);
        }
    }

    layerT<2, 16, 2, 0>(P.w + OFF_IN, P.b_in, XA, XB, P.out, p0, ntB_h, wave, lane);
    layerT<8, 16, 2, 0>(P.w + OFF_H0, P.b_h0, XB, XA, P.out, p0, ntB_h, wave, lane);
    layerT<8, 16, 2, 0>(P.w + OFF_H1, P.b_h1, XA, XB, P.out, p0, ntB_h, wave, lane);
    layerT<8, 16, 2, 0>(P.w + OFF_H2, P.b_h2, XB, XA, P.out, p0, ntB_h, wave, lane);
    layerT<8, 16, 2, 0>(P.w + OFF_H3, P.b_h3, XA, XB, P.out, p0, ntB_h, wave, lane);
    layerT<10, 16, 2, 0>(P.w + OFF_H4, P.b_h4, XB, XA, P.out, p0, ntB_h, wave, lane); // concat
    layerT<8, 16, 2, 0>(P.w + OFF_H5, P.b_h5, XA, XB, P.out, p0, ntB_h, wave, lane);

    // DE splice into XB groups 32..35. Safe here: h5's entry barrier closed
    // h4's reads of XB[32..39]; h5/out write only XB[0..31]; r1's entry
    // barrier publishes these writes before r1 reads them. Cols 283..287
    // are real zeros (de_v has zeros for d >= 27).
    if (wave < 4)
        *(bf16x8*)(XB + ((size_t)(32 + wave) * 64 + (tid & 63)) * 8) = de_v;

    layerT<8, 16, 2, 0>(P.w + OFF_H6, P.b_h6, XB, XA, P.out, p0, ntB_h, wave, lane);
    layerT<8, 17, 2, 1>(P.w + OFF_OUT, P.b_out, XA, XB, P.out, p0, ntB_h, wave, lane);

    // r1: 8 n-tiles / 8 waves -> NS=1 (reads XB feats+de, writes XA[0..15])
    layerT<9, 8, 1, 0>(P.w + OFF_R1, P.b_r1, XB, XA, P.out, p0, wave, wave, lane);

    // ---- r2 (128 -> 3) + sigmoid; waves 0..3 each take one 16-point tile ----
    __syncthreads();
    if (wave < 4) {
        const int l15 = lane & 15, quad = lane >> 4;
        f32x4 acc = (f32x4){0.f, 0.f, 0.f, 0.f};
        const short* xb = XA + quad * 512 + (wave * 16 + l15) * 8;
#pragma unroll
        for (int kt = 0; kt < 4; ++kt) {
            bf16x8 b = *(const bf16x8*)(xb + kt * 2048);
            bf16x8 a = *(const bf16x8*)(P.w + OFF_R2 + (size_t)(kt * 64 + lane) * 8);
            acc = __builtin_amdgcn_mfma_f32_16x16x32_bf16(a, b, acc, 0, 0, 0);
        }
        if (quad == 0) {                   // rows r = rgb channel
#pragma unroll
            for (int r = 0; r < 3; r++) {
                const float v = acc[r] + P.b_r2[r];
                P.out[(size_t)(p0 + wave * 16 + l15) * 3 + r] = 1.f / (1.f + expf(-v));
            }
        }
    }
}

extern "C" void kernel_launch(void* const* d_in, const int* in_sizes, int n_in,
                              void* d_out, int out_size, void* d_ws, size_t ws_size,
                              hipStream_t stream) {
    short* ws = (short*)d_ws;

    PrepP pp;
    pp.W[0]  = (const float*)d_in[2];   // W_in
    pp.W[1]  = (const float*)d_in[4];   // W_h0
    pp.W[2]  = (const float*)d_in[6];   // W_h1
    pp.W[3]  = (const float*)d_in[8];   // W_h2
    pp.W[4]  = (const float*)d_in[10];  // W_h3
    pp.W[5]  = (const float*)d_in[12];  // W_h4
    pp.W[6]  = (const float*)d_in[14];  // W_h5
    pp.W[7]  = (const float*)d_in[16];  // W_h6
    pp.W[8]  = (const float*)d_in[18];  // W_out
    pp.W[9]  = (const float*)d_in[20];  // W_r1
    pp.W[10] = (const float*)d_in[22];  // W_r2
    pp.ws = ws;
    hipLaunchKernelGGL(prep_all, dim3((WS_TOTAL + 255) / 256), dim3(256), 0, stream, pp);

    Params P;
    P.pos  = (const float*)d_in[0];
    P.dir  = (const float*)d_in[1];
    P.b_in = (const float*)d_in[3];
    P.b_h0 = (const float*)d_in[5];
    P.b_h1 = (const float*)d_in[7];
    P.b_h2 = (const float*)d_in[9];
    P.b_h3 = (const float*)d_in[11];
    P.b_h4 = (const float*)d_in[13];
    P.b_h5 = (const float*)d_in[15];
    P.b_h6 = (const float*)d_in[17];
    P.b_out = (const float*)d_in[19];
    P.b_r1 = (const float*)d_in[21];
    P.b_r2 = (const float*)d_in[23];
    P.w = ws;
    P.out = (float*)d_out;
    hipLaunchKernelGGL(nerf_fused, dim3(NPTS / MT), dim3(512), 0, stream, P);
}